// Round 9
// baseline (276.022 us; speedup 1.0000x reference)
//
#include <hip/hip_runtime.h>

#define B_   512
#define N_   512
#define FIN_ 2
#define F_   128
#define G_   512           // 4*F gates
#define XSTRIDE 1040       // floats per x row in LDS (pad -> disjoint banks)
#define H8STRIDE 320       // bytes per h row in LDS (banks disjoint across rows)

typedef int         int4_   __attribute__((ext_vector_type(4)));
typedef float       float4_ __attribute__((ext_vector_type(4)));
typedef float       float2_ __attribute__((ext_vector_type(2)));

#define LOG2E_  1.44269504f
#define LOG2E2_ 2.88539008f

// One LSTM step, two batch rows mapped to MFMA A-rows 0 and 4, i8 K=64.
// preact = (hq @ wq) * invs + (x-proj + bias)   -- i32 accumulation is EXACT;
// error comes only from h quant (scale 127) and per-column w quant (colmax).
// C layout (shape-determined, m89): col=lane&15, row=(lane>>4)*4+reg; A-row
// pattern repeats with period 8 -> lanes 32-63 compute duplicates (benign,
// dup h-writes redirected to dummy LDS rows).
template<bool PF>
__device__ __forceinline__ void lstm_step(
    const signed char* hsrc,         // per-lane: h8[buf] + hrow*H8STRIDE
    signed char* hdst,               // per-lane write slot (incl dummy rows)
    float* outp,                     // per-lane HBM slot
    const int4_ (&wq)[4][2], const float (&invs)[4],
    const float (&w0r)[4], const float (&w1r)[4], const float (&br)[4],
    int4_ (&acc)[4], float2_ xv, float& cs, int grp,
    const float* xpf, float2_& pf1, float2_& pf2)
{
    // A-fragments: slice i covers k = i*64 + grp*16 + [0,16)  (consecutive-16
    // per lane, extrapolated from the verified f16 consecutive-8 layout).
    const int4_ a0 = *reinterpret_cast<const int4_*>(hsrc + grp * 16);
    const int4_ a1 = *reinterpret_cast<const int4_*>(hsrc + 64 + grp * 16);

    // x prefetch for future steps: after af reads, before MFMAs.
    if (PF) {
        pf1 = *reinterpret_cast<const float2_*>(xpf);
        pf2 = *reinterpret_cast<const float2_*>(xpf + 2);
    }

    // fp32-exact x-projection + bias (computed while MFMAs run).
    float xp[4];
#pragma unroll
    for (int t = 0; t < 4; ++t)
        xp[t] = fmaf(xv[0], w0r[t], fmaf(xv[1], w1r[t], br[t]));

    // i32 C-init reg0 = 0; regs 1-3 stale (never read).
#pragma unroll
    for (int t = 0; t < 4; ++t) acc[t][0] = 0;

    // hq @ wq : 4 gate-tiles x 2 K-slices (K=128 total)
#pragma unroll
    for (int t = 0; t < 4; ++t)
        acc[t] = __builtin_amdgcn_mfma_i32_16x16x64_i8(a0, wq[t][0], acc[t], 0, 0, 0);
    acc[2] = __builtin_amdgcn_mfma_i32_16x16x64_i8(a1, wq[2][1], acc[2], 0, 0, 0);
    acc[0] = __builtin_amdgcn_mfma_i32_16x16x64_i8(a1, wq[0][1], acc[0], 0, 0, 0);
    acc[1] = __builtin_amdgcn_mfma_i32_16x16x64_i8(a1, wq[1][1], acc[1], 0, 0, 0);
    acc[3] = __builtin_amdgcn_mfma_i32_16x16x64_i8(a1, wq[3][1], acc[3], 0, 0, 0);

    // Dequant + gate math (fp32), g-first for the cs-critical chain.
    const float pg = fmaf((float)acc[2][0], invs[2], xp[2]);
    const float pi = fmaf((float)acc[0][0], invs[0], xp[0]);
    const float pf_ = fmaf((float)acc[1][0], invs[1], xp[1]);
    const float eg = __builtin_amdgcn_exp2f(LOG2E2_ * pg);
    const float ei = __builtin_amdgcn_exp2f(-LOG2E_ * pi);
    const float ef = __builtin_amdgcn_exp2f(-LOG2E_ * pf_);
    const float rg = __builtin_amdgcn_rcpf(1.f + eg);   // (1-tanh(g))/2 form
    const float ri = __builtin_amdgcn_rcpf(1.f + ei);   // sigmoid(i)
    const float rf = __builtin_amdgcn_rcpf(1.f + ef);   // sigmoid(f)
    const float gg = fmaf(-2.f, rg, 1.f);               // tanh(g)
    cs = fmaf(rf, cs, ri * gg);
    const float po = fmaf((float)acc[3][0], invs[3], xp[3]);
    const float eo = __builtin_amdgcn_exp2f(-LOG2E_ * po);          // off-path
    const float ec = __builtin_amdgcn_exp2f(LOG2E2_ * cs);
    const float ro = __builtin_amdgcn_rcpf(1.f + eo);   // sigmoid(o)
    const float rc = __builtin_amdgcn_rcpf(1.f + ec);
    const float h = fmaf(-2.f * ro, rc, ro);            // o * tanh(cs), fp32

    // Recurrence carries i8-quantized h; OUTPUT path stays fp32-clean.
    const int q = (int)rintf(h * 127.f);
    *hdst = (signed char)q;           // LDS write first: it gates the barrier
    *outp = h;                        // fire-and-forget; nothing waits vmcnt
    asm volatile("s_waitcnt lgkmcnt(0)\n\ts_barrier" ::: "memory");
}

__global__ void __launch_bounds__(512)
lstm_scan(const float* __restrict__ inp, const float* __restrict__ Wk,
          const float* __restrict__ bias, float* __restrict__ out)
{
    const int bb   = blockIdx.x;       // batch rows 2bb, 2bb+1
    const int tid  = threadIdx.x;
    const int w    = tid >> 6;         // wave 0..7, dims [w*16, w*16+16)
    const int lane = tid & 63;
    const int c15  = lane & 15;
    const int grp  = lane >> 4;        // k-group (16 consecutive k per slice)

    __shared__ __align__(16) signed char h8[2][4 * H8STRIDE];  // rows 0,1 + 2 dummy
    __shared__ __align__(64) float x_lds[2 * XSTRIDE];

    // ---- one-time: per-column scales + i8 weight fragments ----
    // tile t = gate t, col = t*128 + w*16 + c15
    float w0r[4], w1r[4], br[4], invs[4], scl[4];
    int cols[4];
#pragma unroll
    for (int t = 0; t < 4; ++t) {
        const int col = t * F_ + w * 16 + c15;
        cols[t] = col;
        w0r[t] = Wk[col];
        w1r[t] = Wk[G_ + col];
        br[t]  = bias[col];
        float cm = 1e-20f;
        for (int k = 0; k < F_; ++k)
            cm = fmaxf(cm, fabsf(Wk[(size_t)(2 + k) * G_ + col]));
        scl[t]  = 127.f / cm;
        invs[t] = cm / (127.f * 127.f);   // dequant: acc * invs = sum h*w
    }
    int4_ wq[4][2];
#pragma unroll
    for (int t = 0; t < 4; ++t)
#pragma unroll
        for (int i = 0; i < 2; ++i) {
            union { int4_ v; signed char c[16]; } u;
#pragma unroll
            for (int e = 0; e < 16; ++e) {
                const int k = i * 64 + grp * 16 + e;
                const float wv = Wk[(size_t)(2 + k) * G_ + cols[t]] * scl[t];
                int q = (int)rintf(wv);
                q = q > 127 ? 127 : (q < -127 ? -127 : q);
                u.c[e] = (signed char)q;
            }
            wq[t][i] = u.v;
        }

    // ---- stage x (2 rows x 1024 floats) into padded LDS ----
    {
        const float* xsrc = inp + (size_t)(2 * bb) * (N_ * FIN_);
        const int i4 = tid * 4;                      // 0..2044
        float4_ v = *reinterpret_cast<const float4_*>(xsrc + i4);
        const int row = i4 >> 10, idx = i4 & 1023;
        *reinterpret_cast<float4_*>(&x_lds[row * XSTRIDE + idx]) = v;
    }
    for (int i = tid; i < 2 * 4 * H8STRIDE; i += 512)
        ((signed char*)h8)[i] = 0;
    __syncthreads();

    const int r    = (lane >> 4) & 1;   // batch sub-row this lane handles
    const int hrow = (c15 >> 2) & 1;    // h-row feeding this lane's A slot
    const int wrow = r + ((lane >> 5) << 1);  // lanes 32-63 -> dummy rows 2,3

    const signed char* hr0 = &h8[0][hrow * H8STRIDE];
    const signed char* hr1 = &h8[1][hrow * H8STRIDE];
    signed char* hw0 = &h8[0][wrow * H8STRIDE + w * 16 + c15];
    signed char* hw1 = &h8[1][wrow * H8STRIDE + w * 16 + c15];
    const float* xq = &x_lds[r * XSTRIDE];   // x for step s lives at xq[2(s-1)]
    float* outp = out + (size_t)(2 * bb + r) * N_ * F_ + w * 16 + c15;

    float cs = 0.f;
    int4_ acc[4];
#pragma unroll
    for (int t = 0; t < 4; ++t) { acc[t][0] = 0; acc[t][1] = 0; acc[t][2] = 0; acc[t][3] = 0; }

    float2_ xz; xz[0] = 0.f; xz[1] = 0.f;
    float2_ pf1, pf2;

    // step 0: x_shift = 0, reads zeroed buf0, writes buf1; prefetch x(1,2)
    lstm_step<true>(hr0, hw1, outp, wq, invs, w0r, w1r, br, acc, xz, cs, grp,
                    xq, pf1, pf2);
    outp += F_;

    // steps 1..510 in pairs (odd reads buf1, even reads buf0)
    for (int i = 0; i < 255; ++i) {
        const float2_ xv1 = pf1;          // x for step 2i+1
        const float2_ xv2 = pf2;          // x for step 2i+2
        lstm_step<true>(hr1, hw0, outp, wq, invs, w0r, w1r, br, acc, xv1, cs,
                        grp, xq + 4 * i + 4, pf1, pf2);
        outp += F_;
        lstm_step<false>(hr0, hw1, outp, wq, invs, w0r, w1r, br, acc, xv2, cs,
                         grp, nullptr, pf1, pf2);
        outp += F_;
    }
    // step 511 (odd): reads buf1; pf1 = x for step 511
    lstm_step<false>(hr1, hw0, outp, wq, invs, w0r, w1r, br, acc, pf1, cs,
                     grp, nullptr, pf1, pf2);
}

extern "C" void kernel_launch(void* const* d_in, const int* in_sizes, int n_in,
                              void* d_out, int out_size, void* d_ws, size_t ws_size,
                              hipStream_t stream) {
    const float* inp  = (const float*)d_in[0];
    const float* Wk   = (const float*)d_in[1];
    const float* bias = (const float*)d_in[2];
    float* out        = (float*)d_out;
    lstm_scan<<<dim3(B_ / 2), dim3(512), 0, stream>>>(inp, Wk, bias, out);
}

// Round 10
// 228.396 us; speedup vs baseline: 1.2085x; 1.2085x over previous
//
#include <hip/hip_runtime.h>

#define B_   512
#define N_   512
#define FIN_ 2
#define F_   128
#define G_   512           // 4*F gates
#define XSTRIDE 1040       // floats per x row in LDS (pad -> disjoint banks)
#define H8STRIDE 320       // bytes per h row in LDS (banks disjoint across rows)

typedef int         int4_   __attribute__((ext_vector_type(4)));
typedef float       float4_ __attribute__((ext_vector_type(4)));
typedef float       float2_ __attribute__((ext_vector_type(2)));

#define LOG2E_  1.44269504f
#define LOG2E2_ 2.88539008f

// ---------- precompute kernel: per-column scales + i8 weights -> d_ws ------
// Bit-identical to the former in-kernel quantization (same op order).
// ws layout: [0, 64K): qw[col*128 + k] (i8)   [64K, 72K): sc[col*4 + {w0,w1,b,invs}]
__global__ void __launch_bounds__(256)
lstm_prep(const float* __restrict__ Wk, const float* __restrict__ bias,
          signed char* __restrict__ qw, float* __restrict__ sc)
{
    const int col = blockIdx.x * 256 + threadIdx.x;   // 0..511
    float cm = 1e-20f;
    for (int k = 0; k < F_; ++k)
        cm = fmaxf(cm, fabsf(Wk[(size_t)(2 + k) * G_ + col]));
    const float scale = 127.f / cm;
    sc[col * 4 + 0] = Wk[col];
    sc[col * 4 + 1] = Wk[G_ + col];
    sc[col * 4 + 2] = bias[col];
    sc[col * 4 + 3] = cm / (127.f * 127.f);
    for (int k = 0; k < F_; ++k) {
        const float wv = Wk[(size_t)(2 + k) * G_ + col] * scale;
        int q = (int)rintf(wv);
        q = q > 127 ? 127 : (q < -127 ? -127 : q);
        qw[col * F_ + k] = (signed char)q;
    }
}

// One LSTM step, two batch rows mapped to MFMA A-rows 0 and 4, i8 K=64.
// preact = (hq @ wq) * invs + (x-proj + bias)   -- i32 accumulation is EXACT.
// C layout: col=lane&15, row=(lane>>4)*4+reg; A-row pattern repeats with
// period 8 -> lanes 32-63 compute duplicates (dup h-writes to dummy rows).
template<bool PF>
__device__ __forceinline__ void lstm_step(
    const signed char* hsrc,         // per-lane: h8[buf] + hrow*H8STRIDE
    signed char* hdst,               // per-lane write slot (incl dummy rows)
    float* outp,                     // per-lane HBM slot
    const int4_ (&wq)[4][2], const float (&invs)[4],
    const float (&w0r)[4], const float (&w1r)[4], const float (&br)[4],
    int4_ (&acc)[4], float2_ xv, float& cs, int grp,
    const float* xpf, float2_& pf1, float2_& pf2)
{
    // A-fragments: slice i covers k = i*64 + grp*16 + [0,16).
    const int4_ a0 = *reinterpret_cast<const int4_*>(hsrc + grp * 16);
    const int4_ a1 = *reinterpret_cast<const int4_*>(hsrc + 64 + grp * 16);

    // x prefetch for future steps: after af reads, before MFMAs.
    if (PF) {
        pf1 = *reinterpret_cast<const float2_*>(xpf);
        pf2 = *reinterpret_cast<const float2_*>(xpf + 2);
    }

    // fp32-exact x-projection + bias (computed while MFMAs run).
    float xp[4];
#pragma unroll
    for (int t = 0; t < 4; ++t)
        xp[t] = fmaf(xv[0], w0r[t], fmaf(xv[1], w1r[t], br[t]));

    // i32 C-init reg0 = 0; regs 1-3 stale (never read).
#pragma unroll
    for (int t = 0; t < 4; ++t) acc[t][0] = 0;

    // hq @ wq : 4 gate-tiles x 2 K-slices (K=128 total); g-tile first so the
    // cs-critical chain starts earliest.
    acc[2] = __builtin_amdgcn_mfma_i32_16x16x64_i8(a0, wq[2][0], acc[2], 0, 0, 0);
    acc[0] = __builtin_amdgcn_mfma_i32_16x16x64_i8(a0, wq[0][0], acc[0], 0, 0, 0);
    acc[1] = __builtin_amdgcn_mfma_i32_16x16x64_i8(a0, wq[1][0], acc[1], 0, 0, 0);
    acc[3] = __builtin_amdgcn_mfma_i32_16x16x64_i8(a0, wq[3][0], acc[3], 0, 0, 0);
    acc[2] = __builtin_amdgcn_mfma_i32_16x16x64_i8(a1, wq[2][1], acc[2], 0, 0, 0);
    acc[0] = __builtin_amdgcn_mfma_i32_16x16x64_i8(a1, wq[0][1], acc[0], 0, 0, 0);
    acc[1] = __builtin_amdgcn_mfma_i32_16x16x64_i8(a1, wq[1][1], acc[1], 0, 0, 0);
    acc[3] = __builtin_amdgcn_mfma_i32_16x16x64_i8(a1, wq[3][1], acc[3], 0, 0, 0);

    // Dequant + gate math (fp32), g-first for the cs-critical chain.
    const float pg = fmaf((float)acc[2][0], invs[2], xp[2]);
    const float pi = fmaf((float)acc[0][0], invs[0], xp[0]);
    const float pf_ = fmaf((float)acc[1][0], invs[1], xp[1]);
    const float eg = __builtin_amdgcn_exp2f(LOG2E2_ * pg);
    const float ei = __builtin_amdgcn_exp2f(-LOG2E_ * pi);
    const float ef = __builtin_amdgcn_exp2f(-LOG2E_ * pf_);
    const float rg = __builtin_amdgcn_rcpf(1.f + eg);   // (1-tanh(g))/2 form
    const float ri = __builtin_amdgcn_rcpf(1.f + ei);   // sigmoid(i)
    const float rf = __builtin_amdgcn_rcpf(1.f + ef);   // sigmoid(f)
    const float gg = fmaf(-2.f, rg, 1.f);               // tanh(g)
    cs = fmaf(rf, cs, ri * gg);
    const float po = fmaf((float)acc[3][0], invs[3], xp[3]);
    const float eo = __builtin_amdgcn_exp2f(-LOG2E_ * po);          // off-path
    const float ec = __builtin_amdgcn_exp2f(LOG2E2_ * cs);
    const float ro = __builtin_amdgcn_rcpf(1.f + eo);   // sigmoid(o)
    const float rc = __builtin_amdgcn_rcpf(1.f + ec);
    const float h = fmaf(-2.f * ro, rc, ro);            // o * tanh(cs), fp32

    // Recurrence carries i8-quantized h; OUTPUT path stays fp32-clean.
    const int q = (int)rintf(h * 127.f);
    *hdst = (signed char)q;           // LDS write first: it gates the barrier
    *outp = h;                        // fire-and-forget; nothing waits vmcnt
    asm volatile("s_waitcnt lgkmcnt(0)\n\ts_barrier" ::: "memory");
}

__global__ void __launch_bounds__(512)
lstm_scan(const float* __restrict__ inp, const signed char* __restrict__ qw,
          const float* __restrict__ sc, float* __restrict__ out)
{
    const int bb   = blockIdx.x;       // batch rows 2bb, 2bb+1
    const int tid  = threadIdx.x;
    const int w    = tid >> 6;         // wave 0..7, dims [w*16, w*16+16)
    const int lane = tid & 63;
    const int c15  = lane & 15;
    const int grp  = lane >> 4;        // k-group (16 consecutive k per slice)

    __shared__ __align__(16) signed char h8[2][4 * H8STRIDE];  // rows 0,1 + 2 dummy
    __shared__ __align__(64) float x_lds[2 * XSTRIDE];

    // ---- preamble: load precomputed scales + i8 fragments (L2-resident) ----
    float w0r[4], w1r[4], br[4], invs[4];
    int4_ wq[4][2];
#pragma unroll
    for (int t = 0; t < 4; ++t) {
        const int col = t * F_ + w * 16 + c15;
        const float4_ s = *reinterpret_cast<const float4_*>(sc + col * 4);
        w0r[t] = s[0]; w1r[t] = s[1]; br[t] = s[2]; invs[t] = s[3];
#pragma unroll
        for (int i = 0; i < 2; ++i)
            wq[t][i] = *reinterpret_cast<const int4_*>(qw + col * F_ + i * 64 + grp * 16);
    }

    // ---- stage x (2 rows x 1024 floats) into padded LDS ----
    {
        const float* xsrc = inp + (size_t)(2 * bb) * (N_ * FIN_);
        const int i4 = tid * 4;                      // 0..2044
        float4_ v = *reinterpret_cast<const float4_*>(xsrc + i4);
        const int row = i4 >> 10, idx = i4 & 1023;
        *reinterpret_cast<float4_*>(&x_lds[row * XSTRIDE + idx]) = v;
    }
    for (int i = tid; i < 2 * 4 * H8STRIDE; i += 512)
        ((signed char*)h8)[i] = 0;
    __syncthreads();

    const int r    = (lane >> 4) & 1;   // batch sub-row this lane handles
    const int hrow = (c15 >> 2) & 1;    // h-row feeding this lane's A slot
    const int wrow = r + ((lane >> 5) << 1);  // lanes 32-63 -> dummy rows 2,3

    const signed char* hr0 = &h8[0][hrow * H8STRIDE];
    const signed char* hr1 = &h8[1][hrow * H8STRIDE];
    signed char* hw0 = &h8[0][wrow * H8STRIDE + w * 16 + c15];
    signed char* hw1 = &h8[1][wrow * H8STRIDE + w * 16 + c15];
    const float* xq = &x_lds[r * XSTRIDE];   // x for step s lives at xq[2(s-1)]
    float* outp = out + (size_t)(2 * bb + r) * N_ * F_ + w * 16 + c15;

    float cs = 0.f;
    int4_ acc[4];
#pragma unroll
    for (int t = 0; t < 4; ++t) { acc[t][0] = 0; acc[t][1] = 0; acc[t][2] = 0; acc[t][3] = 0; }

    float2_ xz; xz[0] = 0.f; xz[1] = 0.f;
    float2_ pf1, pf2;

    // step 0: x_shift = 0, reads zeroed buf0, writes buf1; prefetch x(1,2)
    lstm_step<true>(hr0, hw1, outp, wq, invs, w0r, w1r, br, acc, xz, cs, grp,
                    xq, pf1, pf2);
    outp += F_;

    // steps 1..510 in pairs (odd reads buf1, even reads buf0)
    for (int i = 0; i < 255; ++i) {
        const float2_ xv1 = pf1;          // x for step 2i+1
        const float2_ xv2 = pf2;          // x for step 2i+2
        lstm_step<true>(hr1, hw0, outp, wq, invs, w0r, w1r, br, acc, xv1, cs,
                        grp, xq + 4 * i + 4, pf1, pf2);
        outp += F_;
        lstm_step<false>(hr0, hw1, outp, wq, invs, w0r, w1r, br, acc, xv2, cs,
                         grp, nullptr, pf1, pf2);
        outp += F_;
    }
    // step 511 (odd): reads buf1; pf1 = x for step 511
    lstm_step<false>(hr1, hw0, outp, wq, invs, w0r, w1r, br, acc, pf1, cs,
                     grp, nullptr, pf1, pf2);
}

extern "C" void kernel_launch(void* const* d_in, const int* in_sizes, int n_in,
                              void* d_out, int out_size, void* d_ws, size_t ws_size,
                              hipStream_t stream) {
    const float* inp  = (const float*)d_in[0];
    const float* Wk   = (const float*)d_in[1];
    const float* bias = (const float*)d_in[2];
    float* out        = (float*)d_out;
    signed char* qw = (signed char*)d_ws;                    // 64 KB
    float* sc       = (float*)((char*)d_ws + 64 * 1024);     // 8 KB
    lstm_prep<<<dim3(2), dim3(256), 0, stream>>>(Wk, bias, qw, sc);
    lstm_scan<<<dim3(B_ / 2), dim3(512), 0, stream>>>(inp, qw, sc, out);
}

// Round 11
// 206.555 us; speedup vs baseline: 1.3363x; 1.1057x over previous
//
#include <hip/hip_runtime.h>

#define B_   512
#define N_   512
#define FIN_ 2
#define F_   128
#define G_   512           // 4*F gates
#define XSTRIDE 1040       // floats per x row in LDS (pad -> disjoint banks)
#define H8STRIDE 320       // bytes per h row in LDS (banks disjoint across rows)

typedef int         int4_   __attribute__((ext_vector_type(4)));
typedef float       float4_ __attribute__((ext_vector_type(4)));
typedef float       float2_ __attribute__((ext_vector_type(2)));

#define LOG2E_  1.44269504f
#define LOG2E2_ 2.88539008f

// ---------- precompute kernel: prefolded scales + i8 weights -> d_ws -------
// Scales are prefolded with the exp2 argument constant per gate:
//   i,f,o: sgn=-log2(e)   g: sgn=+2*log2(e)
// so the main loop computes e = exp2(acc*invs' + xp') with NO extra mul.
// qw is bit-identical to R8/R9 (same op order).
__global__ void __launch_bounds__(256)
lstm_prep(const float* __restrict__ Wk, const float* __restrict__ bias,
          signed char* __restrict__ qw, float* __restrict__ sc)
{
    const int col = blockIdx.x * 256 + threadIdx.x;   // 0..511
    const int g = col >> 7;                           // gate index 0..3
    const float sgn = (g == 2) ? LOG2E2_ : -LOG2E_;
    float cm = 1e-20f;
    for (int k = 0; k < F_; ++k)
        cm = fmaxf(cm, fabsf(Wk[(size_t)(2 + k) * G_ + col]));
    const float scale = 127.f / cm;
    sc[col * 4 + 0] = sgn * Wk[col];
    sc[col * 4 + 1] = sgn * Wk[G_ + col];
    sc[col * 4 + 2] = sgn * bias[col];
    sc[col * 4 + 3] = sgn * (cm / (127.f * 127.f));
    for (int k = 0; k < F_; ++k) {
        const float wv = Wk[(size_t)(2 + k) * G_ + col] * scale;
        int q = (int)rintf(wv);
        q = q > 127 ? 127 : (q < -127 ? -127 : q);
        qw[col * F_ + k] = (signed char)q;
    }
}

// One LSTM step, two batch rows on MFMA A-rows 0,4 (pattern repeats at 8,12).
// Gate-split: C rows 8,12 (lanes 32-63) duplicate rows 0,4 (lanes 0-31), so
// instead of recomputing, lanes<32 evaluate sigma(i),sigma(f) while their dup
// partner (lane^32) evaluates tanh(g),sigma(o); two ds_bpermute(lane^32)
// deliver {tanh g, sigma o} for the cs-chain. Trans/wave: 10 -> 6.
template<bool PF>
__device__ __forceinline__ void lstm_step(
    const signed char* hsrc,         // per-lane: h8[buf] + hrow*H8STRIDE
    signed char* hdst,               // per-lane write slot (incl dummy rows)
    float* outp,                     // per-lane HBM slot (lanes<32 store)
    const int4_ (&wq)[4][2], const int4_& z4, const float (&scl)[8],
    float2_ xv, float& cs, int grp, int bpaddr, bool lo32,
    const float* xpf, float2_& pf1, float2_& pf2)
{
    // A-fragments: slice i covers k = i*64 + grp*16 + [0,16).
    const int4_ a0 = *reinterpret_cast<const int4_*>(hsrc + grp * 16);
    const int4_ a1 = *reinterpret_cast<const int4_*>(hsrc + 64 + grp * 16);

    // x prefetch for future steps: after af reads, before MFMAs.
    if (PF) {
        pf1 = *reinterpret_cast<const float2_*>(xpf);
        pf2 = *reinterpret_cast<const float2_*>(xpf + 2);
    }

    // Per-lane x-projection for this lane's TWO gates (prefolded units).
    const float xpA = fmaf(xv[0], scl[0], fmaf(xv[1], scl[1], scl[2]));
    const float xpB = fmaf(xv[0], scl[4], fmaf(xv[1], scl[5], scl[6]));

    // hq @ wq : first MFMA per tile takes zero C directly (no acc pre-init).
    // Tiles 0,2 (i,g) finish first: the cndmask pair is ready early.
    int4_ acc0 = __builtin_amdgcn_mfma_i32_16x16x64_i8(a0, wq[0][0], z4, 0, 0, 0);
    int4_ acc2 = __builtin_amdgcn_mfma_i32_16x16x64_i8(a0, wq[2][0], z4, 0, 0, 0);
    int4_ acc1 = __builtin_amdgcn_mfma_i32_16x16x64_i8(a0, wq[1][0], z4, 0, 0, 0);
    int4_ acc3 = __builtin_amdgcn_mfma_i32_16x16x64_i8(a0, wq[3][0], z4, 0, 0, 0);
    acc0 = __builtin_amdgcn_mfma_i32_16x16x64_i8(a1, wq[0][1], acc0, 0, 0, 0);
    acc2 = __builtin_amdgcn_mfma_i32_16x16x64_i8(a1, wq[2][1], acc2, 0, 0, 0);
    acc1 = __builtin_amdgcn_mfma_i32_16x16x64_i8(a1, wq[1][1], acc1, 0, 0, 0);
    acc3 = __builtin_amdgcn_mfma_i32_16x16x64_i8(a1, wq[3][1], acc3, 0, 0, 0);

    // Split gate math: lanes<32 -> {i,f}; lanes>=32 -> {g,o} (of the SAME
    // (dim,row) unit, via the duplicated acc values).
    const int sA = lo32 ? acc0[0] : acc2[0];
    const int sB = lo32 ? acc1[0] : acc3[0];
    const float pA = fmaf((float)sA, scl[3], xpA);   // prefolded exp2 arg
    const float pB = fmaf((float)sB, scl[7], xpB);
    const float eA = __builtin_amdgcn_exp2f(pA);
    const float eB = __builtin_amdgcn_exp2f(pB);
    const float rA = __builtin_amdgcn_rcpf(1.f + eA);  // sig(i) | inner(g)
    const float rB = __builtin_amdgcn_rcpf(1.f + eB);  // sig(f) | sig(o)
    const float g1 = fmaf(-2.f, rA, 1.f);              // tanh(g) in hi lanes
    const int qg = __builtin_amdgcn_ds_bpermute(bpaddr, __float_as_int(g1));
    const int qo = __builtin_amdgcn_ds_bpermute(bpaddr, __float_as_int(rB));
    const float gg = __int_as_float(qg);               // lanes<32: tanh(g)
    const float ro = __int_as_float(qo);               // lanes<32: sig(o)
    cs = fmaf(rB, cs, rA * gg);                        // sig(f)*cs + sig(i)*tanh(g)
    const float ec = __builtin_amdgcn_exp2f(LOG2E2_ * cs);
    const float rc = __builtin_amdgcn_rcpf(1.f + ec);
    const float h = fmaf(-2.f * ro, rc, ro);           // o * tanh(cs)

    // Recurrence carries i8-quantized h (hi lanes -> dummy rows, garbage ok).
    const int q = (int)rintf(h * 127.f);
    *hdst = (signed char)q;           // LDS write first: it gates the barrier
    if (lo32) *outp = h;              // fire-and-forget; hi lanes hold garbage
    asm volatile("s_waitcnt lgkmcnt(0)\n\ts_barrier" ::: "memory");
}

__global__ void __launch_bounds__(512)
lstm_scan(const float* __restrict__ inp, const signed char* __restrict__ qw,
          const float* __restrict__ sc, float* __restrict__ out)
{
    const int bb   = blockIdx.x;       // batch rows 2bb, 2bb+1
    const int tid  = threadIdx.x;
    const int w    = tid >> 6;         // wave 0..7, dims [w*16, w*16+16)
    const int lane = tid & 63;
    const int c15  = lane & 15;
    const int grp  = lane >> 4;        // k-group (16 consecutive k per slice)
    const bool lo32 = lane < 32;
    const int bpaddr = (lane ^ 32) << 2;   // ds_bpermute byte index

    __shared__ __align__(16) signed char h8[2][4 * H8STRIDE];  // rows 0,1 + 2 dummy
    __shared__ __align__(64) float x_lds[2 * XSTRIDE];

    // ---- preamble: precomputed i8 fragments + this lane's 2-gate scales ----
    int4_ wq[4][2];
#pragma unroll
    for (int t = 0; t < 4; ++t) {
        const int col = t * F_ + w * 16 + c15;
#pragma unroll
        for (int i = 0; i < 2; ++i)
            wq[t][i] = *reinterpret_cast<const int4_*>(qw + col * F_ + i * 64 + grp * 16);
    }
    float scl[8];   // {w0,w1,b,invs} for gate A (i|g) and gate B (f|o)
    {
        const int tA = lo32 ? 0 : 2;               // i | g
        const int colA = tA * F_ + w * 16 + c15;
        const float4_ sa = *reinterpret_cast<const float4_*>(sc + colA * 4);
        const float4_ sb = *reinterpret_cast<const float4_*>(sc + (colA + F_) * 4);
        scl[0] = sa[0]; scl[1] = sa[1]; scl[2] = sa[2]; scl[3] = sa[3];
        scl[4] = sb[0]; scl[5] = sb[1]; scl[6] = sb[2]; scl[7] = sb[3];
    }

    // ---- stage x (2 rows x 1024 floats) into padded LDS ----
    {
        const float* xsrc = inp + (size_t)(2 * bb) * (N_ * FIN_);
        const int i4 = tid * 4;                      // 0..2044
        float4_ v = *reinterpret_cast<const float4_*>(xsrc + i4);
        const int row = i4 >> 10, idx = i4 & 1023;
        *reinterpret_cast<float4_*>(&x_lds[row * XSTRIDE + idx]) = v;
    }
    for (int i = tid; i < 2 * 4 * H8STRIDE; i += 512)
        ((signed char*)h8)[i] = 0;
    __syncthreads();

    const int r    = (lane >> 4) & 1;   // batch sub-row this lane handles
    const int hrow = (c15 >> 2) & 1;    // h-row feeding this lane's A slot
    const int wrow = r + ((lane >> 5) << 1);  // lanes 32-63 -> dummy rows 2,3

    const signed char* hr0 = &h8[0][hrow * H8STRIDE];
    const signed char* hr1 = &h8[1][hrow * H8STRIDE];
    signed char* hw0 = &h8[0][wrow * H8STRIDE + w * 16 + c15];
    signed char* hw1 = &h8[1][wrow * H8STRIDE + w * 16 + c15];
    const float* xq = &x_lds[r * XSTRIDE];   // x for step s lives at xq[2(s-1)]
    float* outp = out + (size_t)(2 * bb + r) * N_ * F_ + w * 16 + c15;

    float cs = 0.f;
    const int4_ z4 = {0, 0, 0, 0};
    float2_ xz; xz[0] = 0.f; xz[1] = 0.f;
    float2_ pf1, pf2;

    // step 0: x_shift = 0, reads zeroed buf0, writes buf1; prefetch x(1,2)
    lstm_step<true>(hr0, hw1, outp, wq, z4, scl, xz, cs, grp, bpaddr, lo32,
                    xq, pf1, pf2);
    outp += F_;

    // steps 1..510 in pairs (odd reads buf1, even reads buf0)
    for (int i = 0; i < 255; ++i) {
        const float2_ xv1 = pf1;          // x for step 2i+1
        const float2_ xv2 = pf2;          // x for step 2i+2
        lstm_step<true>(hr1, hw0, outp, wq, z4, scl, xv1, cs, grp, bpaddr,
                        lo32, xq + 4 * i + 4, pf1, pf2);
        outp += F_;
        lstm_step<false>(hr0, hw1, outp, wq, z4, scl, xv2, cs, grp, bpaddr,
                         lo32, nullptr, pf1, pf2);
        outp += F_;
    }
    // step 511 (odd): reads buf1; pf1 = x for step 511
    lstm_step<false>(hr1, hw0, outp, wq, z4, scl, pf1, cs, grp, bpaddr,
                     lo32, nullptr, pf1, pf2);
}

extern "C" void kernel_launch(void* const* d_in, const int* in_sizes, int n_in,
                              void* d_out, int out_size, void* d_ws, size_t ws_size,
                              hipStream_t stream) {
    const float* inp  = (const float*)d_in[0];
    const float* Wk   = (const float*)d_in[1];
    const float* bias = (const float*)d_in[2];
    float* out        = (float*)d_out;
    signed char* qw = (signed char*)d_ws;                    // 64 KB
    float* sc       = (float*)((char*)d_ws + 64 * 1024);     // 8 KB
    lstm_prep<<<dim3(2), dim3(256), 0, stream>>>(Wk, bias, qw, sc);
    lstm_scan<<<dim3(B_ / 2), dim3(512), 0, stream>>>(inp, qw, sc, out);
}